// Round 1
// baseline (322.859 us; speedup 1.0000x reference)
//
#include <hip/hip_runtime.h>
#include <hip/hip_bf16.h>

typedef unsigned short u16;
typedef __attribute__((ext_vector_type(8))) __bf16 bf16x8;
typedef __attribute__((ext_vector_type(4))) float f32x4;

__device__ __forceinline__ u16 f2bf(float f) {
    union { float f; unsigned u; } v; v.f = f;
    unsigned u = v.u;
    unsigned r = (u + 0x7FFFu + ((u >> 16) & 1u)) >> 16;   // RTNE
    return (u16)r;
}

// ---------------- fp32 -> bf16 convert (float4 / ushort4 vectorized) --------
__global__ void cvt_f32_bf16(const float4* __restrict__ src,
                             ushort4* __restrict__ dst, int n4) {
    int i = blockIdx.x * blockDim.x + threadIdx.x;
    if (i < n4) {
        float4 a = src[i];
        ushort4 o;
        o.x = f2bf(a.x); o.y = f2bf(a.y); o.z = f2bf(a.z); o.w = f2bf(a.w);
        dst[i] = o;
    }
}

// ---------------- bf16 NT GEMM, m97 structure (128x128 tile, BK=32) ---------
// C[m,n] = sum_k A[m,k] * B[n,k]  (both row-major, K contiguous)
// MODE 0: epilogue v = tanhf(acc + bias[n]); write fp32 Cf and bf16 Cbf
//         A split: k<2048 from A0 (lda 2048), k>=2048 from A1 (lda 2048)
// MODE 1: epilogue v = acc + bias[n]; write fp32 Cf only; A = A0, lda = K
#define BM 128
#define BN 128
#define BK 32

template<int MODE>
__global__ __launch_bounds__(256, 2)
void gemm_bt(const u16* __restrict__ A0, const u16* __restrict__ A1,
             const u16* __restrict__ Bm, const float* __restrict__ bias,
             float* __restrict__ Cf, u16* __restrict__ Cbf,
             int M, int N, int K)
{
    __shared__ u16 Alds[BM * BK];   // 8 KB
    __shared__ u16 Blds[BN * BK];   // 8 KB

    const int tid  = threadIdx.x;
    const int wave = tid >> 6;
    const int lane = tid & 63;
    const int nTiles = N / BN;
    const int mB = (int)blockIdx.x / nTiles;
    const int nB = (int)blockIdx.x % nTiles;
    const int m0 = mB * BM;
    const int n0 = nB * BN;

    const int wr = wave >> 1;        // 0..1  (wave's M sub-tile)
    const int wc = wave & 1;         // 0..1  (wave's N sub-tile)
    const int fr = lane & 15;        // fragment row/col index
    const int fq = lane >> 4;        // fragment k-group (0..3)

    f32x4 acc[4][4];
    #pragma unroll
    for (int i = 0; i < 4; ++i)
        #pragma unroll
        for (int j = 0; j < 4; ++j)
            acc[i][j] = f32x4{0.f, 0.f, 0.f, 0.f};

    const int lda   = (MODE == 0) ? 2048 : K;
    const int arow  = lane >> 2;         // 0..15 (row within 16-row stripe)
    const int acolc = (lane & 3) * 8;    // 16B chunk within BK=32 row

    for (int k0 = 0; k0 < K; k0 += BK) {
        const u16* Asrc;
        int kc;
        if (MODE == 0) { Asrc = (k0 < 2048) ? A0 : A1; kc = k0 & 2047; }
        else           { Asrc = A0;                    kc = k0;        }

        // stage A tile: each wave stages rows [wave*32, wave*32+32)
        #pragma unroll
        for (int j = 0; j < 2; ++j) {
            int row = wave * 32 + j * 16 + arow;
            const u16* g = Asrc + (size_t)(m0 + row) * lda + kc + acolc;
            __builtin_amdgcn_global_load_lds(
                (const __attribute__((address_space(1))) unsigned int*)g,
                (__attribute__((address_space(3))) unsigned int*)&Alds[(wave * 32 + j * 16) * BK],
                16, 0, 0);
        }
        // stage B tile
        #pragma unroll
        for (int j = 0; j < 2; ++j) {
            int row = wave * 32 + j * 16 + arow;
            const u16* g = Bm + (size_t)(n0 + row) * K + k0 + acolc;
            __builtin_amdgcn_global_load_lds(
                (const __attribute__((address_space(1))) unsigned int*)g,
                (__attribute__((address_space(3))) unsigned int*)&Blds[(wave * 32 + j * 16) * BK],
                16, 0, 0);
        }
        __syncthreads();   // drains vmcnt before barrier (compiler-emitted)

        bf16x8 af[4], bfr[4];
        #pragma unroll
        for (int i = 0; i < 4; ++i)
            af[i] = *reinterpret_cast<const bf16x8*>(
                &Alds[(wr * 64 + i * 16 + fr) * BK + fq * 8]);
        #pragma unroll
        for (int j = 0; j < 4; ++j)
            bfr[j] = *reinterpret_cast<const bf16x8*>(
                &Blds[(wc * 64 + j * 16 + fr) * BK + fq * 8]);

        #pragma unroll
        for (int i = 0; i < 4; ++i)
            #pragma unroll
            for (int j = 0; j < 4; ++j)
                acc[i][j] = __builtin_amdgcn_mfma_f32_16x16x32_bf16(
                    af[i], bfr[j], acc[i][j], 0, 0, 0);

        __syncthreads();
    }

    // epilogue: C/D layout col = lane&15, row = (lane>>4)*4 + reg
    #pragma unroll
    for (int i = 0; i < 4; ++i) {
        #pragma unroll
        for (int j = 0; j < 4; ++j) {
            int col = n0 + wc * 64 + j * 16 + fr;
            float bv = bias[col];
            #pragma unroll
            for (int r = 0; r < 4; ++r) {
                int row = m0 + wr * 64 + i * 16 + fq * 4 + r;
                float v = acc[i][j][r] + bv;
                if constexpr (MODE == 0) {
                    v = tanhf(v);
                    Cf[(size_t)row * N + col]  = v;
                    Cbf[(size_t)row * N + col] = f2bf(v);
                } else {
                    Cf[(size_t)row * N + col] = v;
                }
            }
        }
    }
}

extern "C" void kernel_launch(void* const* d_in, const int* in_sizes, int n_in,
                              void* d_out, int out_size, void* d_ws, size_t ws_size,
                              hipStream_t stream) {
    const float* x   = (const float*)d_in[0];   // [B, I]
    const float* hid = (const float*)d_in[1];   // [B, H]
    const float* Wih = (const float*)d_in[2];   // [H, I+H]
    const float* bih = (const float*)d_in[3];   // [H]
    const float* Who = (const float*)d_in[4];   // [O, H]
    const float* bho = (const float*)d_in[5];   // [O]
    float* out = (float*)d_out;

    const int B = 4096, I = 2048, H = 2048, O = 2048;

    // workspace layout (bf16), total ~75.5 MB
    u16* x_bf   = (u16*)d_ws;                     // B*I
    u16* h_bf   = x_bf   + (size_t)B * I;         // B*H
    u16* wih_bf = h_bf   + (size_t)B * H;         // H*(I+H)
    u16* who_bf = wih_bf + (size_t)H * (I + H);   // O*H
    u16* nh_bf  = who_bf + (size_t)O * H;         // B*H

    auto cvt = [&](const float* s, u16* d, size_t n) {
        int n4 = (int)(n / 4);
        cvt_f32_bf16<<<dim3((n4 + 255) / 256), dim3(256), 0, stream>>>(
            (const float4*)s, (ushort4*)d, n4);
    };
    cvt(x,   x_bf,   (size_t)B * I);
    cvt(hid, h_bf,   (size_t)B * H);
    cvt(Wih, wih_bf, (size_t)H * (I + H));
    cvt(Who, who_bf, (size_t)O * H);

    float* out_y  = out;                    // [B, O] (output 0)
    float* out_nh = out + (size_t)B * O;    // [B, H] (output 1)

    // GEMM1: new_hidden = tanh([x,hid] @ W_ih^T + b_ih)
    gemm_bt<0><<<dim3((B / 128) * (H / 128)), dim3(256), 0, stream>>>(
        x_bf, h_bf, wih_bf, bih, out_nh, nh_bf, B, H, I + H);

    // GEMM2: output = new_hidden @ W_ho^T + b_ho
    gemm_bt<1><<<dim3((B / 128) * (O / 128)), dim3(256), 0, stream>>>(
        nh_bf, nh_bf, who_bf, bho, out_y, nullptr, B, O, H);
}

// Round 3
// 289.877 us; speedup vs baseline: 1.1138x; 1.1138x over previous
//
#include <hip/hip_runtime.h>
#include <hip/hip_bf16.h>

typedef unsigned short u16;
typedef __attribute__((ext_vector_type(8))) __bf16 bf16x8;
typedef __attribute__((ext_vector_type(4))) float f32x4;

#define AS1 __attribute__((address_space(1)))
#define AS3 __attribute__((address_space(3)))

__device__ __forceinline__ u16 f2bf(float f) {
    union { float f; unsigned u; } v; v.f = f;
    unsigned u = v.u;
    return (u16)((u + 0x7FFFu + ((u >> 16) & 1u)) >> 16);   // RTNE
}

// ---- fused fp32 -> bf16 convert for all 4 tensors (grid-stride) ------------
__global__ void cvt4(const float4* __restrict__ a, const float4* __restrict__ b,
                     const float4* __restrict__ c, const float4* __restrict__ d,
                     ushort4* __restrict__ oa, ushort4* __restrict__ ob,
                     ushort4* __restrict__ oc, ushort4* __restrict__ od,
                     int na, int nb, int nc, int nd) {
    const int total = na + nb + nc + nd;
    for (int i = blockIdx.x * blockDim.x + threadIdx.x; i < total;
         i += gridDim.x * blockDim.x) {
        const float4* s; ushort4* o; int j = i;
        if (j < na) { s = a; o = oa; }
        else {
            j -= na;
            if (j < nb) { s = b; o = ob; }
            else {
                j -= nb;
                if (j < nc) { s = c; o = oc; }
                else        { j -= nc; s = d; o = od; }
            }
        }
        float4 v = s[j];
        ushort4 u;
        u.x = f2bf(v.x); u.y = f2bf(v.y); u.z = f2bf(v.z); u.w = f2bf(v.w);
        o[j] = u;
    }
}

// ---- bf16 NT GEMM: BM=256, BN=128, BK=64, 8 waves (4M x 2N), 64x64/wave ----
// Triple-buffered LDS, stage t+2 while computing t, counted vmcnt(6).
// LDS per buffer: A 256x64 bf16 = 16384 u16, B 128x64 = 8192 u16; stride 24576.
// Swizzle: logical 16B chunk cl (0..7 within a 64-u16 row) stored at physical
// chunk cl ^ (row&7). gload_lds dest is LINEAR (wave base + lane*16B); the
// per-lane GLOBAL source address applies the inverse permutation (involution),
// ds_reads apply it again (rule #21: both-sides-or-neither).
template<int MODE>
__global__ __launch_bounds__(512, 2)
void gemm_bt(const u16* __restrict__ A0, const u16* __restrict__ A1,
             const u16* __restrict__ Bm, const float* __restrict__ bias,
             float* __restrict__ Cf, u16* __restrict__ Cbf,
             int M, int N, int K)
{
    extern __shared__ u16 lds[];
    const int tid  = threadIdx.x;
    const int wave = tid >> 6;
    const int lane = tid & 63;

    const int nN  = N >> 7;                 // tiles along N (BN=128)
    const int nwg = (M >> 8) * nN;          // total tiles (BM=256)
    // T1: XCD-aware swizzle (nwg divisible by 8)
    const int id  = ((int)blockIdx.x % 8) * (nwg >> 3) + (int)blockIdx.x / 8;
    const int m0  = (id / nN) << 8;
    const int n0  = (id % nN) << 7;

    const int fr = lane & 15, fq = lane >> 4;
    const int wr = wave >> 1, wc = wave & 1;

    // staging: per-lane source mapping (inverse swizzle), linear LDS dest
    const int srow   = tid >> 3;                       // row within 64-row round
    const int schunk = (tid & 7) ^ (srow & 7);         // logical source chunk
    const int ldsW   = wave << 9;                      // wave*512 u16 dest base

    f32x4 acc[4][4];
    #pragma unroll
    for (int i = 0; i < 4; ++i)
        #pragma unroll
        for (int j = 0; j < 4; ++j)
            acc[i][j] = f32x4{0.f, 0.f, 0.f, 0.f};

    const int lda = (MODE == 0) ? 2048 : K;

    auto stage = [&](int t) {
        const int k0  = t << 6;
        const int buf = (t % 3) * 24576;
        const u16* As; int kc;
        if constexpr (MODE == 0) { As = (k0 < 2048) ? A0 : A1; kc = k0 & 2047; }
        else                     { As = A0;                    kc = k0;        }
        #pragma unroll
        for (int r = 0; r < 4; ++r) {   // A: 4 rounds x 64 rows
            const u16* g = As + (size_t)(m0 + (r << 6) + srow) * lda + kc + (schunk << 3);
            __builtin_amdgcn_global_load_lds((const AS1 unsigned int*)g,
                (AS3 unsigned int*)&lds[buf + (r << 12) + ldsW], 16, 0, 0);
        }
        #pragma unroll
        for (int r = 0; r < 2; ++r) {   // B: 2 rounds x 64 rows
            const u16* g = Bm + (size_t)(n0 + (r << 6) + srow) * K + k0 + (schunk << 3);
            __builtin_amdgcn_global_load_lds((const AS1 unsigned int*)g,
                (AS3 unsigned int*)&lds[buf + 16384 + (r << 12) + ldsW], 16, 0, 0);
        }
    };

    // read-side swizzled chunk offsets (row&7 == fr&7 for all our rows)
    const int ax0 = ((fq)     ^ (fr & 7)) << 3;   // ksub 0: logical chunk fq
    const int ax1 = ((4 + fq) ^ (fr & 7)) << 3;   // ksub 1: logical chunk 4+fq
    const int aoff = ((wr << 6) + fr) << 6;       // row*64 u16
    const int boff = ((wc << 6) + fr) << 6;

    const int nt = K >> 6;

    // prologue: stage tiles 0,1; wait tile 0 (newest 6 loads may remain)
    stage(0); stage(1);
    asm volatile("s_waitcnt vmcnt(6)" ::: "memory");
    __builtin_amdgcn_s_barrier();

    for (int t = 0; t < nt; ++t) {
        const int buf = (t % 3) * 24576;
        if (t + 2 < nt) stage(t + 2);   // into buf[(t+2)%3] == buf[(t-1)%3], already consumed

        bf16x8 a0[4], a1[4], b0[4], b1[4];
        #pragma unroll
        for (int i = 0; i < 4; ++i) {
            a0[i] = *(const bf16x8*)&lds[buf + aoff + (i << 10) + ax0];
            a1[i] = *(const bf16x8*)&lds[buf + aoff + (i << 10) + ax1];
        }
        #pragma unroll
        for (int j = 0; j < 4; ++j) {
            b0[j] = *(const bf16x8*)&lds[buf + 16384 + boff + (j << 10) + ax0];
            b1[j] = *(const bf16x8*)&lds[buf + 16384 + boff + (j << 10) + ax1];
        }

        __builtin_amdgcn_s_setprio(1);
        #pragma unroll
        for (int i = 0; i < 4; ++i)
            #pragma unroll
            for (int j = 0; j < 4; ++j) {
                acc[i][j] = __builtin_amdgcn_mfma_f32_16x16x32_bf16(a0[i], b0[j], acc[i][j], 0, 0, 0);
                acc[i][j] = __builtin_amdgcn_mfma_f32_16x16x32_bf16(a1[i], b1[j], acc[i][j], 0, 0, 0);
            }
        __builtin_amdgcn_s_setprio(0);

        if (t + 1 < nt) {
            // counted wait: the 6 loads staged THIS iter (tile t+2) may stay
            // in flight; everything older (tile t+1) must have landed.
            if (t + 2 < nt) asm volatile("s_waitcnt vmcnt(6)" ::: "memory");
            else            asm volatile("s_waitcnt vmcnt(0)" ::: "memory");
            __builtin_amdgcn_s_barrier();
        }
    }

    // epilogue: C/D layout col = lane&15, row = (lane>>4)*4 + reg
    #pragma unroll
    for (int j = 0; j < 4; ++j) {
        const int col = n0 + (wc << 6) + (j << 4) + fr;
        const float bv = bias[col];
        #pragma unroll
        for (int i = 0; i < 4; ++i) {
            #pragma unroll
            for (int r = 0; r < 4; ++r) {
                const int row = m0 + (wr << 6) + (i << 4) + (fq << 2) + r;
                float v = acc[i][j][r] + bv;
                if constexpr (MODE == 0) {
                    v = tanhf(v);
                    Cf[(size_t)row * N + col]  = v;
                    Cbf[(size_t)row * N + col] = f2bf(v);
                } else {
                    Cf[(size_t)row * N + col] = v;
                }
            }
        }
    }
}

extern "C" void kernel_launch(void* const* d_in, const int* in_sizes, int n_in,
                              void* d_out, int out_size, void* d_ws, size_t ws_size,
                              hipStream_t stream) {
    const float* x   = (const float*)d_in[0];   // [B, I]
    const float* hid = (const float*)d_in[1];   // [B, H]
    const float* Wih = (const float*)d_in[2];   // [H, I+H]
    const float* bih = (const float*)d_in[3];   // [H]
    const float* Who = (const float*)d_in[4];   // [O, H]
    const float* bho = (const float*)d_in[5];   // [O]
    float* out = (float*)d_out;

    const int B = 4096, I = 2048, H = 2048, O = 2048;

    u16* x_bf   = (u16*)d_ws;                     // B*I
    u16* h_bf   = x_bf   + (size_t)B * I;         // B*H
    u16* wih_bf = h_bf   + (size_t)B * H;         // H*(I+H)
    u16* who_bf = wih_bf + (size_t)H * (I + H);   // O*H
    u16* nh_bf  = who_bf + (size_t)O * H;         // B*H

    const int na = (B * I) / 4, nb = (B * H) / 4,
              nc = (H * (I + H)) / 4, nd = (O * H) / 4;
    cvt4<<<dim3(2048), dim3(256), 0, stream>>>(
        (const float4*)x, (const float4*)hid, (const float4*)Wih, (const float4*)Who,
        (ushort4*)x_bf, (ushort4*)h_bf, (ushort4*)wih_bf, (ushort4*)who_bf,
        na, nb, nc, nd);

    float* out_y  = out;                    // [B, O]
    float* out_nh = out + (size_t)B * O;    // [B, H]

    const size_t shmem = 3 * 24576 * sizeof(u16);   // 147456 B
    // hipFuncSetAttribute is host-side (not a stream op) — graph-capture safe.
    hipFuncSetAttribute(reinterpret_cast<const void*>(&gemm_bt<0>),
                        hipFuncAttributeMaxDynamicSharedMemorySize, (int)shmem);
    hipFuncSetAttribute(reinterpret_cast<const void*>(&gemm_bt<1>),
                        hipFuncAttributeMaxDynamicSharedMemorySize, (int)shmem);

    // GEMM1: new_hidden = tanh([x,hid] @ W_ih^T + b_ih)   M=4096,N=2048,K=4096
    gemm_bt<0><<<dim3((B / 256) * (H / 128)), dim3(512), shmem, stream>>>(
        x_bf, h_bf, wih_bf, bih, out_nh, nh_bf, B, H, I + H);

    // GEMM2: output = new_hidden @ W_ho^T + b_ho          M=4096,N=2048,K=2048
    gemm_bt<1><<<dim3((B / 256) * (O / 128)), dim3(512), shmem, stream>>>(
        nh_bf, nh_bf, who_bf, bho, out_y, nullptr, B, O, H);
}